// Round 12
// baseline (803.403 us; speedup 1.0000x reference)
//
#include <hip/hip_runtime.h>
#include <cstdint>

#define B_ 4
#define H_ 16
#define S_ 2048
#define D_ 64

// fold temperature (1/8) and log2(e) into q so exp(x) == exp2(scaled dot)
#define QSCALE (0.125f * 1.44269504088896f)

typedef _Float16 half8 __attribute__((ext_vector_type(8)));
typedef float f32x4 __attribute__((ext_vector_type(4)));
typedef float f32x16 __attribute__((ext_vector_type(16)));
typedef uint32_t u32x2 __attribute__((ext_vector_type(2)));
typedef uint32_t u32x4 __attribute__((ext_vector_type(4)));

// ---------- pre-kernels (FAST path) ----------

__global__ void cvt_qk_kernel(const float* __restrict__ q, const float* __restrict__ k,
                              _Float16* __restrict__ qh, _Float16* __restrict__ kh) {
    const int64_t N = (int64_t)B_ * H_ * S_ * D_;
    const int64_t step = (int64_t)gridDim.x * blockDim.x * 4;
    for (int64_t i = ((int64_t)blockIdx.x * blockDim.x + threadIdx.x) * 4; i < N; i += step) {
        float4 a = *reinterpret_cast<const float4*>(q + i);
        float4 b = *reinterpret_cast<const float4*>(k + i);
        _Float16 ah[4] = { (_Float16)(a.x * QSCALE), (_Float16)(a.y * QSCALE),
                           (_Float16)(a.z * QSCALE), (_Float16)(a.w * QSCALE) };
        _Float16 bh[4] = { (_Float16)b.x, (_Float16)b.y, (_Float16)b.z, (_Float16)b.w };
        *reinterpret_cast<u32x2*>(qh + i) = *reinterpret_cast<u32x2*>(ah);
        *reinterpret_cast<u32x2*>(kh + i) = *reinterpret_cast<u32x2*>(bh);
    }
}

// V [b,h,s,d] fp32 -> Vt [b,h,d,s] fp16
__global__ void transpose_v_kernel(const float* __restrict__ v, _Float16* __restrict__ vt) {
    const int bh = blockIdx.y;
    const int k0 = blockIdx.x * 64;
    const float* vp = v + (int64_t)bh * S_ * D_;
    _Float16* vtp = vt + (int64_t)bh * D_ * S_;
    const int t = threadIdx.x;
    const int d = t & 63;
    const int kc = t >> 6;
    _Float16 tmp[16];
#pragma unroll
    for (int j = 0; j < 16; ++j)
        tmp[j] = (_Float16)vp[(int64_t)(k0 + kc * 16 + j) * D_ + d];
    half8 a, b;
#pragma unroll
    for (int j = 0; j < 8; ++j) { a[j] = tmp[j]; b[j] = tmp[8 + j]; }
    half8* dst = reinterpret_cast<half8*>(vtp + (int64_t)d * S_ + k0 + kc * 16);
    dst[0] = a; dst[1] = b;
}

// mask int32 [b,q,k] -> bitmask; bit (k%32) of word (b*S+q)*64 + k/32
__global__ void pack_mask_kernel(const int* __restrict__ mask, uint32_t* __restrict__ mbits) {
    const int64_t groups = (int64_t)B_ * S_ * S_ / 64;
    const int lane = threadIdx.x & 63;
    const int64_t wstep = ((int64_t)gridDim.x * blockDim.x) >> 6;
    for (int64_t g = ((int64_t)blockIdx.x * blockDim.x + threadIdx.x) >> 6; g < groups; g += wstep) {
        int mv = mask[g * 64 + lane];
        unsigned long long bits = __ballot(mv != 0);
        if (lane == 0)
            *reinterpret_cast<unsigned long long*>(mbits + g * 2) = bits;
    }
}

// ---------- main attention kernel ----------
// Structure = Round-8 body + XCD decode + 1-deep K prefetch in BOTH passes.
// Key scheduling invariant: the NEXT tile's K loads are issued BEFORE this
// tile's attn stores. vmcnt completion is counted in-order per wave, so a
// load issued after stores cannot be waited on until the stores ack; issuing
// K first removes the store stream from the QK critical path.
// __launch_bounds__(256,4) pins total regs <= 128 (arch+acc) so occupancy
// stays 4 waves/SIMD (R9 regression root-cause: 144 regs -> 21% occupancy).

template<bool FAST>
__global__ __launch_bounds__(256, 4) void attn_main(
    const float* __restrict__ qf, const float* __restrict__ kf, const float* __restrict__ vf,
    const int* __restrict__ maskI,
    const _Float16* __restrict__ qh, const _Float16* __restrict__ kh, const _Float16* __restrict__ vt,
    const uint32_t* __restrict__ mbits,
    float* __restrict__ out, float* __restrict__ attn)
{
    const int tid = threadIdx.x;
    const int w = tid >> 6;
    const int lane = tid & 63;
    const int c = lane & 31;
    const int hi = lane >> 5;

    // ---- XCD-aware decode (bijective on 1024 blocks; neutral but harmless) ----
    const int fid = blockIdx.x;
    const int xcd = fid & 7;
    const int slot = fid >> 3;              // 0..127
    const int p = xcd + 8 * (slot >> 4);    // 0..63  == b*H + h
    const int x = slot & 15;                // q-tile index
    const int b = p >> 4;

    const int qw = x * 128 + w * 32;
    const int64_t bh = p;
    const int64_t qrow = (int64_t)b * S_ + qw + c;   // mask row for this lane

    half8 aq[4];
    if (FAST) {
        const _Float16* qp = qh + (bh * S_ + qw + c) * D_ + hi * 8;
#pragma unroll
        for (int kk = 0; kk < 4; ++kk)
            aq[kk] = *reinterpret_cast<const half8*>(qp + kk * 16);
    } else {
        const float* qp = qf + (bh * S_ + qw + c) * D_ + hi * 8;
#pragma unroll
        for (int kk = 0; kk < 4; ++kk)
#pragma unroll
            for (int j = 0; j < 8; ++j)
                aq[kk][j] = (_Float16)(qp[kk * 16 + j] * QSCALE);
    }

    const uint32_t* mrow = FAST ? (mbits + qrow * (S_ / 32)) : nullptr;

    auto loadK = [&](half8 (&kr)[4], int t) {
        const int k0 = t * 32;
        if (FAST) {
            const _Float16* kp = kh + (bh * S_ + k0 + c) * D_ + hi * 8;
#pragma unroll
            for (int kk = 0; kk < 4; ++kk)
                kr[kk] = *reinterpret_cast<const half8*>(kp + kk * 16);
        } else {
            const float* kp = kf + (bh * S_ + k0 + c) * D_ + hi * 8;
#pragma unroll
            for (int kk = 0; kk < 4; ++kk)
#pragma unroll
                for (int j = 0; j < 8; ++j)
                    kr[kk][j] = (_Float16)kp[kk * 16 + j];
        }
    };

    auto qk = [&](const half8 (&kr)[4]) -> f32x16 {
        f32x16 acc;
#pragma unroll
        for (int r = 0; r < 16; ++r) acc[r] = 0.f;
#pragma unroll
        for (int kk = 0; kk < 4; ++kk)
            acc = __builtin_amdgcn_mfma_f32_32x32x16_f16(kr[kk], aq[kk], acc, 0, 0, 0);
        return acc;
    };

    // ================= Pass A: per-lane denominator =================
    float l = 0.f;
    {
        auto bodyA = [&](const half8 (&kr)[4], uint32_t mwf, int t) -> float {
            f32x16 acc = qk(kr);
            const int k0 = t * 32;
            const uint32_t mw = mwf >> (hi * 4);
            float e[16];
#pragma unroll
            for (int r = 0; r < 16; ++r) {
                bool dead;
                if (FAST) {
                    dead = ((mw >> ((r & 3) + 8 * (r >> 2))) & 1u) == 0u;
                } else {
                    const int key = k0 + (r & 3) + 8 * (r >> 2) + 4 * hi;
                    dead = maskI[qrow * S_ + key] == 0;
                }
                e[r] = __builtin_exp2f(dead ? -1e30f : acc[r]);
            }
#pragma unroll
            for (int st = 1; st < 16; st <<= 1)
#pragma unroll
                for (int i = 0; i < 16; i += 2 * st) e[i] += e[i + st];
            return e[0];
        };

        half8 ka[4], kb[4];
        loadK(ka, 0);
        for (int t = 0; t < 64; t += 2) {
            uint32_t m0 = 0, m1 = 0;
            if (FAST) {
                u32x2 mq = *reinterpret_cast<const u32x2*>(mrow + t);
                m0 = mq[0]; m1 = mq[1];
            }
            loadK(kb, t + 1);
            l += bodyA(ka, m0, t);
            if (t + 2 < 64) loadK(ka, t + 2);
            l += bodyA(kb, m1, t + 1);
        }
    }
    const float lt = l + __shfl_xor(l, 32);
    const float rinv = 1.0f / lt;

    // ================= Pass B: recompute, normalize, store attn, PV =================
    f32x16 o0, o1;
#pragma unroll
    for (int r = 0; r < 16; ++r) { o0[r] = 0.f; o1[r] = 0.f; }

    {
        auto bodyB = [&](const half8 (&kr)[4], uint32_t mwf, int t) {
            const int k0 = t * 32;
            f32x16 acc = qk(kr);
            const uint32_t mw = mwf >> (hi * 4);

            float* arow = attn + (bh * S_ + qw + c) * (int64_t)S_ + k0 + 4 * hi;
            uint32_t pk[8];
#pragma unroll
            for (int g4 = 0; g4 < 4; ++g4) {
                f32x4 pq;
#pragma unroll
                for (int e2 = 0; e2 < 4; ++e2) {
                    const int r = g4 * 4 + e2;
                    bool dead;
                    if (FAST) {
                        dead = ((mw >> (8 * g4 + e2)) & 1u) == 0u;
                    } else {
                        const int key = k0 + e2 + 8 * g4 + 4 * hi;
                        dead = maskI[qrow * S_ + key] == 0;
                    }
                    pq[e2] = __builtin_exp2f(dead ? -1e30f : acc[r]) * rinv;
                }
                *reinterpret_cast<f32x4*>(arow + 8 * g4) = pq;   // regular cached store
                pk[2 * g4]     = __builtin_bit_cast(uint32_t, __builtin_amdgcn_cvt_pkrtz(pq[0], pq[1]));
                pk[2 * g4 + 1] = __builtin_bit_cast(uint32_t, __builtin_amdgcn_cvt_pkrtz(pq[2], pq[3]));
            }

            u32x2 rA = __builtin_amdgcn_permlane32_swap(pk[0], pk[2], false, false);
            u32x2 rB = __builtin_amdgcn_permlane32_swap(pk[1], pk[3], false, false);
            u32x2 rC = __builtin_amdgcn_permlane32_swap(pk[4], pk[6], false, false);
            u32x2 rD = __builtin_amdgcn_permlane32_swap(pk[5], pk[7], false, false);
            u32x4 fa0 = { rA[0], rB[0], rA[1], rB[1] };
            u32x4 fa1 = { rC[0], rD[0], rC[1], rD[1] };
            half8 pa0 = __builtin_bit_cast(half8, fa0);
            half8 pa1 = __builtin_bit_cast(half8, fa1);

            half8 bv00, bv01, bv10, bv11;
            if (FAST) {
                const _Float16* vp = vt + (bh * D_ + c) * S_ + k0 + hi * 8;
                bv00 = *reinterpret_cast<const half8*>(vp);
                bv01 = *reinterpret_cast<const half8*>(vp + 32 * S_);
                bv10 = *reinterpret_cast<const half8*>(vp + 16);
                bv11 = *reinterpret_cast<const half8*>(vp + 16 + 32 * S_);
            } else {
                const float* vp0 = vf + (bh * S_ + k0 + hi * 8) * D_ + c;
                const float* vp1 = vp0 + 16 * D_;
#pragma unroll
                for (int j = 0; j < 8; ++j) {
                    bv00[j] = (_Float16)vp0[j * D_];
                    bv01[j] = (_Float16)vp0[j * D_ + 32];
                    bv10[j] = (_Float16)vp1[j * D_];
                    bv11[j] = (_Float16)vp1[j * D_ + 32];
                }
            }
            o0 = __builtin_amdgcn_mfma_f32_32x32x16_f16(pa0, bv00, o0, 0, 0, 0);
            o1 = __builtin_amdgcn_mfma_f32_32x32x16_f16(pa0, bv01, o1, 0, 0, 0);
            o0 = __builtin_amdgcn_mfma_f32_32x32x16_f16(pa1, bv10, o0, 0, 0, 0);
            o1 = __builtin_amdgcn_mfma_f32_32x32x16_f16(pa1, bv11, o1, 0, 0, 0);
        };

        half8 ka[4], kb[4];
        loadK(ka, 0);
        for (int t = 0; t < 64; t += 2) {
            uint32_t m0 = 0, m1 = 0;
            if (FAST) {
                u32x2 mq = *reinterpret_cast<const u32x2*>(mrow + t);
                m0 = mq[0]; m1 = mq[1];
            }
            loadK(kb, t + 1);                 // issued BEFORE bodyB(ka)'s stores
            bodyB(ka, m0, t);
            if (t + 2 < 64) loadK(ka, t + 2); // issued before bodyB(kb)'s stores
            bodyB(kb, m1, t + 1);
        }
    }

    // ---- out store: lane (c,hi) reg r -> out[qw + rowmap(r,hi)][c and c+32] ----
#pragma unroll
    for (int r = 0; r < 16; ++r) {
        const int row = (r & 3) + 8 * (r >> 2) + 4 * hi;
        float* op = out + (bh * S_ + qw + row) * D_;
        op[c] = o0[r];
        op[c + 32] = o1[r];
    }
}

// ---------- launch ----------
extern "C" void kernel_launch(void* const* d_in, const int* in_sizes, int n_in,
                              void* d_out, int out_size, void* d_ws, size_t ws_size,
                              hipStream_t stream) {
    const float* q = (const float*)d_in[0];
    const float* k = (const float*)d_in[1];
    const float* v = (const float*)d_in[2];
    const int* mask = (const int*)d_in[3];
    float* out = (float*)d_out;
    float* attn = out + (int64_t)B_ * H_ * S_ * D_;

    const size_t nElem = (size_t)B_ * H_ * S_ * D_;           // 8388608
    const size_t maskWords = (size_t)B_ * S_ * (S_ / 32);     // 524288
    const size_t need = nElem * 2 * 3 + maskWords * 4;        // 52,428,800 B

    const int nblk = B_ * H_ * (S_ / 128);                    // 1024
    if (d_ws != nullptr && ws_size >= need) {
        _Float16* qh = (_Float16*)d_ws;
        _Float16* kh = qh + nElem;
        _Float16* vt = kh + nElem;
        uint32_t* mb = (uint32_t*)(vt + nElem);
        cvt_qk_kernel<<<2048, 256, 0, stream>>>(q, k, qh, kh);
        transpose_v_kernel<<<dim3(S_ / 64, B_ * H_), 256, 0, stream>>>(v, vt);
        pack_mask_kernel<<<2048, 256, 0, stream>>>(mask, mb);
        attn_main<true><<<nblk, 256, 0, stream>>>(q, k, v, mask, qh, kh, vt, mb, out, attn);
    } else {
        attn_main<false><<<nblk, 256, 0, stream>>>(q, k, v, mask,
                                                   nullptr, nullptr, nullptr, nullptr, out, attn);
    }
}

// Round 13
// 647.117 us; speedup vs baseline: 1.2415x; 1.2415x over previous
//
#include <hip/hip_runtime.h>
#include <cstdint>

#define B_ 4
#define H_ 16
#define S_ 2048
#define D_ 64

// fold temperature (1/8) and log2(e) into q so exp(x) == exp2(scaled dot)
#define QSCALE (0.125f * 1.44269504088896f)

typedef _Float16 half8 __attribute__((ext_vector_type(8)));
typedef float f32x4 __attribute__((ext_vector_type(4)));
typedef float f32x16 __attribute__((ext_vector_type(16)));
typedef uint32_t u32x2 __attribute__((ext_vector_type(2)));
typedef uint32_t u32x4 __attribute__((ext_vector_type(4)));

// ---------- pre-kernels (FAST path) ----------

// q -> fp16 * QSCALE, row-major (Q fragment loaded once per kernel; scatter ok)
__global__ void cvt_q_kernel(const float* __restrict__ q, _Float16* __restrict__ qh) {
    const int64_t N = (int64_t)B_ * H_ * S_ * D_;
    const int64_t step = (int64_t)gridDim.x * blockDim.x * 4;
    for (int64_t i = ((int64_t)blockIdx.x * blockDim.x + threadIdx.x) * 4; i < N; i += step) {
        float4 a = *reinterpret_cast<const float4*>(q + i);
        _Float16 ah[4] = { (_Float16)(a.x * QSCALE), (_Float16)(a.y * QSCALE),
                           (_Float16)(a.z * QSCALE), (_Float16)(a.w * QSCALE) };
        *reinterpret_cast<u32x2*>(qh + i) = *reinterpret_cast<u32x2*>(ah);
    }
}

// K -> FRAGMENT layout: half8 slot [((bh*64+t)*4+kk)*64 + hi*32 + c]
//   = K[bh][t*32+c][kk*16+hi*8+j]  (j=0..7)
// Main-kernel K loads become lane-consecutive 16B -> fully coalesced.
__global__ void pack_k_kernel(const float* __restrict__ k, _Float16* __restrict__ kh) {
    const int bh = blockIdx.y;
    const int t = blockIdx.x;
    const int tid = threadIdx.x;
    const int kk = tid >> 6, lane = tid & 63, hi = lane >> 5, c = lane & 31;
    const float* src = k + ((int64_t)bh * S_ + t * 32 + c) * D_ + kk * 16 + hi * 8;
    float4 a = *reinterpret_cast<const float4*>(src);
    float4 b2 = *reinterpret_cast<const float4*>(src + 4);
    half8 h = { (_Float16)a.x, (_Float16)a.y, (_Float16)a.z, (_Float16)a.w,
                (_Float16)b2.x, (_Float16)b2.y, (_Float16)b2.z, (_Float16)b2.w };
    half8* dst = reinterpret_cast<half8*>(kh) + (((int64_t)bh * 64 + t) * 4 + kk) * 64 + hi * 32 + c;
    *dst = h;
}

// V -> FRAGMENT layout: half8 slot [((bh*64+t)*8 + g)*32 + c], g = kk*4+hi*2+db
//   = V[bh][t*32 + kk*16 + hi*8 + j][c + 32*db]
__global__ void pack_v_kernel(const float* __restrict__ v, _Float16* __restrict__ vt) {
    const int bh = blockIdx.y;
    const int t = blockIdx.x;
    const int tid = threadIdx.x;
    const int g = tid >> 5, c = tid & 31;
    const int kk = g >> 2, hi = (g >> 1) & 1, db = g & 1;
    const float* src = v + ((int64_t)bh * S_ + t * 32 + kk * 16 + hi * 8) * D_ + c + 32 * db;
    half8 h;
#pragma unroll
    for (int j = 0; j < 8; ++j) h[j] = (_Float16)src[j * D_];
    half8* dst = reinterpret_cast<half8*>(vt) + (((int64_t)bh * 64 + t) * 8 + g) * 32 + c;
    *dst = h;
}

// mask int32 [b,q,k] -> bitmask; bit (k%32) of word (b*S+q)*64 + k/32
__global__ void pack_mask_kernel(const int* __restrict__ mask, uint32_t* __restrict__ mbits) {
    const int64_t groups = (int64_t)B_ * S_ * S_ / 64;
    const int lane = threadIdx.x & 63;
    const int64_t wstep = ((int64_t)gridDim.x * blockDim.x) >> 6;
    for (int64_t g = ((int64_t)blockIdx.x * blockDim.x + threadIdx.x) >> 6; g < groups; g += wstep) {
        int mv = mask[g * 64 + lane];
        unsigned long long bits = __ballot(mv != 0);
        if (lane == 0)
            *reinterpret_cast<unsigned long long*>(mbits + g * 2) = bits;
    }
}

// ---------- main attention kernel ----------
// Body = Round-11 structure (4 independent waves, swapped MFMA, per-lane
// softmax, direct f32x4 attn stores, permlane PV frag, XCD decode).
// THIS ROUND: K/V read from pre-packed FRAGMENT layouts -> every K/V load is
// lane-consecutive (coalesced, 8 line-touches/instr instead of 64). Theory:
// the stable ~680us across 7 variants was TA/L1 throughput on 64-way
// address-divergent loads (512 line-transactions per tile), invisible in
// VALU/MFMA/HBM counters.

template<bool FAST>
__global__ __launch_bounds__(256, 2) void attn_main(
    const float* __restrict__ qf, const float* __restrict__ kf, const float* __restrict__ vf,
    const int* __restrict__ maskI,
    const _Float16* __restrict__ qh, const _Float16* __restrict__ kh, const _Float16* __restrict__ vt,
    const uint32_t* __restrict__ mbits,
    float* __restrict__ out, float* __restrict__ attn)
{
    const int tid = threadIdx.x;
    const int w = tid >> 6;
    const int lane = tid & 63;
    const int c = lane & 31;
    const int hi = lane >> 5;

    // ---- XCD-aware decode (bijective on 1024 blocks) ----
    const int fid = blockIdx.x;
    const int xcd = fid & 7;
    const int slot = fid >> 3;              // 0..127
    const int p = xcd + 8 * (slot >> 4);    // 0..63  == b*H + h
    const int x = slot & 15;                // q-tile index
    const int b = p >> 4;

    const int qw = x * 128 + w * 32;
    const int64_t bh = p;
    const int64_t qrow = (int64_t)b * S_ + qw + c;   // mask row for this lane

    half8 aq[4];
    if (FAST) {
        const _Float16* qp = qh + (bh * S_ + qw + c) * D_ + hi * 8;
#pragma unroll
        for (int kk = 0; kk < 4; ++kk)
            aq[kk] = *reinterpret_cast<const half8*>(qp + kk * 16);
    } else {
        const float* qp = qf + (bh * S_ + qw + c) * D_ + hi * 8;
#pragma unroll
        for (int kk = 0; kk < 4; ++kk)
#pragma unroll
            for (int j = 0; j < 8; ++j)
                aq[kk][j] = (_Float16)(qp[kk * 16 + j] * QSCALE);
    }

    const uint32_t* mrow = FAST ? (mbits + qrow * (S_ / 32)) : nullptr;
    const half8* kbase = FAST ? reinterpret_cast<const half8*>(kh) + (int64_t)bh * 64 * 4 * 64 + hi * 32 + c
                              : nullptr;
    const half8* vbase = FAST ? reinterpret_cast<const half8*>(vt) + (int64_t)bh * 64 * 8 * 32 + c
                              : nullptr;

    // ================= Pass A: per-lane denominator =================
    float l = 0.f;
    for (int g = 0; g < 16; ++g) {
        u32x4 mq;
        if (FAST) mq = *reinterpret_cast<const u32x4*>(mrow + g * 4);
#pragma unroll
        for (int u = 0; u < 4; ++u) {
            const int t = g * 4 + u;
            const int k0 = t * 32;
            f32x16 acc;
#pragma unroll
            for (int r = 0; r < 16; ++r) acc[r] = 0.f;
            if (FAST) {
                const half8* kp8 = kbase + (int64_t)t * 4 * 64;
#pragma unroll
                for (int kk = 0; kk < 4; ++kk) {
                    half8 bk = kp8[kk * 64];   // lane-consecutive: coalesced
                    acc = __builtin_amdgcn_mfma_f32_32x32x16_f16(bk, aq[kk], acc, 0, 0, 0);
                }
            } else {
                const float* kp = kf + (bh * S_ + k0 + c) * D_ + hi * 8;
#pragma unroll
                for (int kk = 0; kk < 4; ++kk) {
                    half8 bk;
#pragma unroll
                    for (int j = 0; j < 8; ++j) bk[j] = (_Float16)kp[kk * 16 + j];
                    acc = __builtin_amdgcn_mfma_f32_32x32x16_f16(bk, aq[kk], acc, 0, 0, 0);
                }
            }
            uint32_t mw = 0;
            if (FAST) mw = mq[u] >> (hi * 4);
            float e[16];
#pragma unroll
            for (int r = 0; r < 16; ++r) {
                bool dead;
                if (FAST) {
                    dead = ((mw >> ((r & 3) + 8 * (r >> 2))) & 1u) == 0u;
                } else {
                    const int key = k0 + (r & 3) + 8 * (r >> 2) + 4 * hi;
                    dead = maskI[qrow * S_ + key] == 0;
                }
                e[r] = __builtin_exp2f(dead ? -1e30f : acc[r]);
            }
#pragma unroll
            for (int st = 1; st < 16; st <<= 1)
#pragma unroll
                for (int i = 0; i < 16; i += 2 * st) e[i] += e[i + st];
            l += e[0];
        }
    }
    const float lt = l + __shfl_xor(l, 32);
    const float rinv = 1.0f / lt;

    // ================= Pass B: recompute, normalize, store attn, PV =================
    f32x16 o0, o1;
#pragma unroll
    for (int r = 0; r < 16; ++r) { o0[r] = 0.f; o1[r] = 0.f; }

    for (int g = 0; g < 16; ++g) {
        u32x4 mq;
        if (FAST) mq = *reinterpret_cast<const u32x4*>(mrow + g * 4);
#pragma unroll
        for (int u = 0; u < 4; ++u) {
            const int t = g * 4 + u;
            const int k0 = t * 32;
            f32x16 acc;
#pragma unroll
            for (int r = 0; r < 16; ++r) acc[r] = 0.f;
            if (FAST) {
                const half8* kp8 = kbase + (int64_t)t * 4 * 64;
#pragma unroll
                for (int kk = 0; kk < 4; ++kk) {
                    half8 bk = kp8[kk * 64];
                    acc = __builtin_amdgcn_mfma_f32_32x32x16_f16(bk, aq[kk], acc, 0, 0, 0);
                }
            } else {
                const float* kp = kf + (bh * S_ + k0 + c) * D_ + hi * 8;
#pragma unroll
                for (int kk = 0; kk < 4; ++kk) {
                    half8 bk;
#pragma unroll
                    for (int j = 0; j < 8; ++j) bk[j] = (_Float16)kp[kk * 16 + j];
                    acc = __builtin_amdgcn_mfma_f32_32x32x16_f16(bk, aq[kk], acc, 0, 0, 0);
                }
            }
            uint32_t mw = 0;
            if (FAST) mw = mq[u] >> (hi * 4);

            float* arow = attn + (bh * S_ + qw + c) * (int64_t)S_ + k0 + 4 * hi;
            uint32_t pk[8];
#pragma unroll
            for (int g4 = 0; g4 < 4; ++g4) {
                f32x4 pq;
#pragma unroll
                for (int e2 = 0; e2 < 4; ++e2) {
                    const int r = g4 * 4 + e2;
                    bool dead;
                    if (FAST) {
                        dead = ((mw >> (8 * g4 + e2)) & 1u) == 0u;
                    } else {
                        const int key = k0 + e2 + 8 * g4 + 4 * hi;
                        dead = maskI[qrow * S_ + key] == 0;
                    }
                    pq[e2] = __builtin_exp2f(dead ? -1e30f : acc[r]) * rinv;
                }
                *reinterpret_cast<f32x4*>(arow + 8 * g4) = pq;
                pk[2 * g4]     = __builtin_bit_cast(uint32_t, __builtin_amdgcn_cvt_pkrtz(pq[0], pq[1]));
                pk[2 * g4 + 1] = __builtin_bit_cast(uint32_t, __builtin_amdgcn_cvt_pkrtz(pq[2], pq[3]));
            }

            u32x2 rA = __builtin_amdgcn_permlane32_swap(pk[0], pk[2], false, false);
            u32x2 rB = __builtin_amdgcn_permlane32_swap(pk[1], pk[3], false, false);
            u32x2 rC = __builtin_amdgcn_permlane32_swap(pk[4], pk[6], false, false);
            u32x2 rD = __builtin_amdgcn_permlane32_swap(pk[5], pk[7], false, false);
            u32x4 fa0 = { rA[0], rB[0], rA[1], rB[1] };
            u32x4 fa1 = { rC[0], rD[0], rC[1], rD[1] };
            half8 pa0 = __builtin_bit_cast(half8, fa0);
            half8 pa1 = __builtin_bit_cast(half8, fa1);

            half8 bv00, bv01, bv10, bv11;
            if (FAST) {
                const half8* vp8 = vbase + (int64_t)t * 8 * 32;
                bv00 = vp8[(0 * 4 + hi * 2 + 0) * 32];   // all coalesced
                bv01 = vp8[(0 * 4 + hi * 2 + 1) * 32];
                bv10 = vp8[(1 * 4 + hi * 2 + 0) * 32];
                bv11 = vp8[(1 * 4 + hi * 2 + 1) * 32];
            } else {
                const float* vp0 = vf + (bh * S_ + k0 + hi * 8) * D_ + c;
                const float* vp1 = vp0 + 16 * D_;
#pragma unroll
                for (int j = 0; j < 8; ++j) {
                    bv00[j] = (_Float16)vp0[j * D_];
                    bv01[j] = (_Float16)vp0[j * D_ + 32];
                    bv10[j] = (_Float16)vp1[j * D_];
                    bv11[j] = (_Float16)vp1[j * D_ + 32];
                }
            }
            o0 = __builtin_amdgcn_mfma_f32_32x32x16_f16(pa0, bv00, o0, 0, 0, 0);
            o1 = __builtin_amdgcn_mfma_f32_32x32x16_f16(pa0, bv01, o1, 0, 0, 0);
            o0 = __builtin_amdgcn_mfma_f32_32x32x16_f16(pa1, bv10, o0, 0, 0, 0);
            o1 = __builtin_amdgcn_mfma_f32_32x32x16_f16(pa1, bv11, o1, 0, 0, 0);
        }
    }

    // ---- out store: lane (c,hi) reg r -> out[qw + rowmap(r,hi)][c and c+32] ----
#pragma unroll
    for (int r = 0; r < 16; ++r) {
        const int row = (r & 3) + 8 * (r >> 2) + 4 * hi;
        float* op = out + (bh * S_ + qw + row) * D_;
        op[c] = o0[r];
        op[c + 32] = o1[r];
    }
}

// ---------- launch ----------
extern "C" void kernel_launch(void* const* d_in, const int* in_sizes, int n_in,
                              void* d_out, int out_size, void* d_ws, size_t ws_size,
                              hipStream_t stream) {
    const float* q = (const float*)d_in[0];
    const float* k = (const float*)d_in[1];
    const float* v = (const float*)d_in[2];
    const int* mask = (const int*)d_in[3];
    float* out = (float*)d_out;
    float* attn = out + (int64_t)B_ * H_ * S_ * D_;

    const size_t nElem = (size_t)B_ * H_ * S_ * D_;           // 8388608
    const size_t maskWords = (size_t)B_ * S_ * (S_ / 32);     // 524288
    const size_t need = nElem * 2 * 3 + maskWords * 4;        // 52,428,800 B

    const int nblk = B_ * H_ * (S_ / 128);                    // 1024
    if (d_ws != nullptr && ws_size >= need) {
        _Float16* qh = (_Float16*)d_ws;
        _Float16* kh = qh + nElem;
        _Float16* vt = kh + nElem;
        uint32_t* mb = (uint32_t*)(vt + nElem);
        cvt_q_kernel<<<1024, 256, 0, stream>>>(q, qh);
        pack_k_kernel<<<dim3(S_ / 32, B_ * H_), 256, 0, stream>>>(k, kh);
        pack_v_kernel<<<dim3(S_ / 32, B_ * H_), 256, 0, stream>>>(v, vt);
        pack_mask_kernel<<<2048, 256, 0, stream>>>(mask, mb);
        attn_main<true><<<nblk, 256, 0, stream>>>(q, k, v, mask, qh, kh, vt, mb, out, attn);
    } else {
        attn_main<false><<<nblk, 256, 0, stream>>>(q, k, v, mask,
                                                   nullptr, nullptr, nullptr, nullptr, out, attn);
    }
}